// Round 6
// baseline (274.288 us; speedup 1.0000x reference)
//
#include <hip/hip_runtime.h>

// PatchEmbedding2 on MI355X — round 6: LDS-free fragment-direct GEMM
//   + XCD-swizzle (12 same-wm blocks -> same XCD => A-slice served from L2)
//   + depth-4 register prefetch pipeline (no barriers => no vmcnt(0) drains).
// r5 evidence: three different GEMM structures all ~80-97us; volume model:
// 64x64 tiles stream A x12 + B x125 = 1.12 GB at ~13.7 TB/s mixed => 82us.
// Fix the serving tier (L2 via swizzle) and the exposed latency (depth 4).
//
// Fragment order (16x16x32 bf16, r2/r5-verified): lane l holds
// X[row=l&15][k=(l>>4)*8+j]. 1KB block per (tile,g). Af[((mt*96+g)*64+l)*8].
// Workspace: 64KB + 4.72MB (Bf) + ~49.2MB (Af) ~= 54 MB.

typedef __attribute__((ext_vector_type(8))) short bf16x8;
typedef __attribute__((ext_vector_type(8))) unsigned short u16x8;
typedef __attribute__((ext_vector_type(4))) float f32x4;

#define K_DIM 3072
#define N_DIM 768

__device__ __forceinline__ unsigned short f2bf(float f) {
  unsigned int u = __float_as_uint(f);
  u += 0x7fffu + ((u >> 16) & 1u);   // RNE
  return (unsigned short)(u >> 16);
}

// ---------------- prep: W -> bf16 fragment order + token layout ----------------
__global__ __launch_bounds__(1024)
void prep_kernel(const float* __restrict__ W, unsigned short* __restrict__ Bf,
                 const float* __restrict__ iw, int P,
                 int* __restrict__ tokBase, int* __restrict__ tokMask, int NB_W) {
  int bid = blockIdx.x;
  int tid = threadIdx.x;
  if (bid < NB_W) {
#pragma unroll
    for (int s = 0; s < 2; ++s) {
      int c = bid * 2048 + tid + s * 1024;
      if (c < 48 * 96 * 64) {
        int l = c & 63;
        int u = c >> 6;
        int g = u % 96;
        int nt = u / 96;
        int n = nt * 16 + (l & 15);
        int k = g * 32 + (l >> 4) * 8;
        const float* src = W + (size_t)n * K_DIM + k;
        float4 f0 = *(const float4*)src;
        float4 f1 = *(const float4*)(src + 4);
        u16x8 o;
        o[0] = f2bf(f0.x); o[1] = f2bf(f0.y); o[2] = f2bf(f0.z); o[3] = f2bf(f0.w);
        o[4] = f2bf(f1.x); o[5] = f2bf(f1.y); o[6] = f2bf(f1.z); o[7] = f2bf(f1.w);
        *(u16x8*)(Bf + (size_t)c * 8) = o;
      }
    }
    return;
  }
  // ---- layout (single block, r2-verified) ----
  __shared__ double s_wsum[16];
  __shared__ double s_avg;
  __shared__ int s_cnt[1024];
  float v = (tid < P) ? iw[tid] : 0.0f;
  double d = (double)v;
#pragma unroll
  for (int off = 32; off > 0; off >>= 1) d += __shfl_down(d, off, 64);
  if ((tid & 63) == 0) s_wsum[tid >> 6] = d;
  __syncthreads();
  if (tid == 0) {
    double s = 0.0;
    for (int i = 0; i < 16; ++i) s += s_wsum[i];
    s_avg = s / (double)P;
  }
  __syncthreads();
  int cnt = 0, sz = 32;
  if (tid < P) {
    double val = 32.0 * pow(s_avg / (double)v, 0.05);
    if (val > 32.0) val = 32.0;
    sz = (val >= 24.0) ? 32 : (val >= 12.0) ? 16 : (val >= 6.0) ? 8 : 4;
    cnt = (sz < 32) ? (32 / sz) : 1;
  }
  s_cnt[tid] = cnt;
  __syncthreads();
  for (int dl = 1; dl < 1024; dl <<= 1) {
    int add = (tid >= dl) ? s_cnt[tid - dl] : 0;
    __syncthreads();
    s_cnt[tid] += add;
    __syncthreads();
  }
  if (tid < P) {
    int off = s_cnt[tid] - cnt;
    int ini_col = (tid * 32) & 1023;
    int ini_row = (tid * 32 * 32) >> 10;
    if (sz == 32) {
      tokBase[off] = ini_row * 1024 + ini_col;
      tokMask[off] = 31;
    } else {
      int ns = 32 / sz;
      for (int j = 0; j < ns; ++j) {
        int r = ini_row + (j * sz) / ns;
        int c = ini_col + ((j * sz) & 31);
        tokBase[off + j] = r * 1024 + c;
        tokMask[off + j] = sz - 1;
      }
    }
  }
}

// ---------------- gather: x -> bf16 A in fragment order (r5-verified) ----------
__global__ __launch_bounds__(256)
void gather_kernel(const float* __restrict__ x,
                   const int* __restrict__ tokBase,
                   const int* __restrict__ tokMask,
                   unsigned short* __restrict__ Af, int T, int Mtot) {
  int mt = blockIdx.x;
  int tid = threadIdx.x;
  int l = tid & 63;
  int g0 = tid >> 6;
  int m = mt * 16 + (l & 15);
  int q = l >> 4;
  bool valid = (m < Mtot);
  int b = 0, base = 0, mask = 31, sh = 5;
  if (valid) {
    b = m / T;
    int t = m - b * T;
    base = tokBase[t];
    mask = tokMask[t];
    sh = __popc(mask);
  }
  const float* xb = x + (size_t)b * 3145728 + base;
  unsigned short* outp = Af + ((size_t)mt * 96 + g0) * 512 + l * 8;
#pragma unroll
  for (int i = 0; i < 24; ++i) {
    int g = g0 + i * 4;
    int k = g * 32 + q * 8;
    u16x8 o = {0, 0, 0, 0, 0, 0, 0, 0};
    if (valid) {
      int c = k >> 10;
      int f = k & 1023;
      if (sh >= 3) {                       // s in {8,16,32}: 8 contiguous floats
        int h = (f >> sh) & mask;
        int w = f & mask;
        const float* s = xb + (size_t)c * 1048576 + h * 1024 + w;
        float4 f0 = *(const float4*)s;
        float4 f1 = *(const float4*)(s + 4);
        o[0] = f2bf(f0.x); o[1] = f2bf(f0.y); o[2] = f2bf(f0.z); o[3] = f2bf(f0.w);
        o[4] = f2bf(f1.x); o[5] = f2bf(f1.y); o[6] = f2bf(f1.z); o[7] = f2bf(f1.w);
      } else {                             // s == 4 generic (unused by this input)
#pragma unroll
        for (int j = 0; j < 8; ++j) {
          int ff = f + j;
          int h = (ff >> sh) & mask;
          int w = ff & mask;
          o[j] = f2bf(xb[(size_t)c * 1048576 + h * 1024 + w]);
        }
      }
    }
    *(u16x8*)(outp + (size_t)i * 2048) = o;
  }
}

// ---------------- gemm: LDS-free, XCD-swizzled, depth-4 pipeline --------------
// bid -> (wm, wn): the 12 blocks of one wm share bid%8 => same XCD (round-robin
// heuristic): bid = (wm%8) + 8*((wm/8)*12 + wn).
__global__ __launch_bounds__(64)
void gemm_kernel(const short* __restrict__ Af, const short* __restrict__ Bf,
                 const float* __restrict__ bias, float* __restrict__ out, int Mtot) {
  int bid = blockIdx.x;
  int c8 = bid & 7;
  int r8 = bid >> 3;
  int wm = (r8 / 12) * 8 + c8;     // 0..127 (125 valid)
  int wn = r8 % 12;
  if (wm >= 125) return;

  int l = threadIdx.x;
  int loff = l * 8;

  const short* pA[4];
  const short* pB[4];
#pragma unroll
  for (int i = 0; i < 4; ++i) pA[i] = Af + ((size_t)(wm * 4 + i) * 96) * 512 + loff;
#pragma unroll
  for (int j = 0; j < 4; ++j) pB[j] = Bf + ((size_t)(wn * 4 + j) * 96) * 512 + loff;

  f32x4 acc[4][4] = {};
  bf16x8 aS[4][4], bS[4][4];       // 4 pipeline slots x 4 frags

#define LOADSET(S, G)                                          \
  {                                                            \
    _Pragma("unroll")                                          \
    for (int i = 0; i < 4; ++i)                                \
      aS[S][i] = *(const bf16x8*)(pA[i] + (G) * 512);          \
    _Pragma("unroll")                                          \
    for (int j = 0; j < 4; ++j)                                \
      bS[S][j] = *(const bf16x8*)(pB[j] + (G) * 512);          \
  }
#define MFMASET(S)                                                           \
  {                                                                          \
    _Pragma("unroll")                                                        \
    for (int i = 0; i < 4; ++i)                                              \
      _Pragma("unroll")                                                      \
      for (int j = 0; j < 4; ++j)                                            \
        acc[i][j] = __builtin_amdgcn_mfma_f32_16x16x32_bf16(aS[S][i], bS[S][j], \
                                                            acc[i][j], 0, 0, 0); \
  }

  LOADSET(0, 0) LOADSET(1, 1) LOADSET(2, 2) LOADSET(3, 3)
  for (int g = 0; g < 96; g += 4) {
    MFMASET(0) if (g + 4 < 96) LOADSET(0, g + 4)
    MFMASET(1) if (g + 5 < 96) LOADSET(1, g + 5)
    MFMASET(2) if (g + 6 < 96) LOADSET(2, g + 6)
    MFMASET(3) if (g + 7 < 96) LOADSET(3, g + 7)
  }
#undef LOADSET
#undef MFMASET

  // epilogue: C/D layout col=lane&15, row=(lane>>4)*4+reg (r2-verified)
  int rr = l & 15, q = l >> 4;
#pragma unroll
  for (int j = 0; j < 4; ++j) {
    int n = wn * 64 + j * 16 + rr;
    float bv = bias[n];
#pragma unroll
    for (int i = 0; i < 4; ++i) {
      int mrow = wm * 64 + i * 16 + q * 4;
#pragma unroll
      for (int r2 = 0; r2 < 4; ++r2) {
        int m = mrow + r2;
        if (m < Mtot) out[(size_t)m * N_DIM + n] = acc[i][j][r2] + bv;
      }
    }
  }
}

extern "C" void kernel_launch(void* const* d_in, const int* in_sizes, int n_in,
                              void* d_out, int out_size, void* d_ws, size_t ws_size,
                              hipStream_t stream) {
  const float* x  = (const float*)d_in[0];
  const float* iw = (const float*)d_in[1];
  const float* W  = (const float*)d_in[2];
  const float* b  = (const float*)d_in[3];
  int P = in_sizes[1];                        // 992
  int B = in_sizes[0] / (3 * 1024 * 1024);    // 8
  int E = in_sizes[3];                        // 768
  int T = out_size / (B * E);                 // 995
  int Mtot = B * T;                           // 7960
  int Mpad = (Mtot + 63) & ~63;               // 8000
  int mtBlocks = Mpad / 16;                   // 500

  char* ws = (char*)d_ws;
  int* tokBase = (int*)ws;                              // 32 KB
  int* tokMask = (int*)(ws + 32768);                    // 32 KB
  unsigned short* Bf = (unsigned short*)(ws + 65536);   // 4.72 MB (frag order)
  unsigned short* Af = (unsigned short*)(ws + 65536 + (size_t)E * K_DIM * 2);

  int NB_W = (48 * 96 * 64 + 2047) / 2048;    // 144
  prep_kernel<<<NB_W + 1, 1024, 0, stream>>>(W, Bf, iw, P, tokBase, tokMask, NB_W);

  gather_kernel<<<mtBlocks, 256, 0, stream>>>(x, tokBase, tokMask, Af, T, Mtot);

  // swizzled grid: 8 * ceil(125/8)*12 = 1536 blocks (wm>=125 guard inside)
  int nBlocks = 8 * ((125 + 7) / 8) * 12;
  gemm_kernel<<<nBlocks, 64, 0, stream>>>((const short*)Af, (const short*)Bf, b,
                                          (float*)d_out, Mtot);
}

// Round 7
// 246.336 us; speedup vs baseline: 1.1135x; 1.1135x over previous
//
#include <hip/hip_runtime.h>

// PatchEmbedding2 on MI355X — round 7.
// Unified model from r2-r6: per-CU vmem return path (~40-60 B/cyc) + per-iter
// barrier-drain latency bound all designs. Fix: 128x128 x BK=64 LDS tiles,
// double-buffered (64 KB), ONE barrier/iter (drain of next tile's
// global_load_lds overlaps current tile's 32 MFMA + 16 ds_read). 48 iters.
// XOR-swizzled 16B chunks (in the GLOBAL src addr — gll LDS dst is fixed
// lane*16) keep frag ds_read_b128 at 2-way bank aliasing (free, m136).
// prep/gather: row-major Ab/Wb (r3/r4-verified).

typedef __attribute__((ext_vector_type(8))) short bf16x8;
typedef __attribute__((ext_vector_type(4))) float f32x4;

#define K_DIM 3072
#define N_DIM 768

__device__ __forceinline__ unsigned short f2bf(float f) {
  unsigned int u = __float_as_uint(f);
  u += 0x7fffu + ((u >> 16) & 1u);   // RNE
  return (unsigned short)(u >> 16);
}

__device__ __forceinline__ void gload16(const void* g, void* l) {
  __builtin_amdgcn_global_load_lds(
      (const __attribute__((address_space(1))) void*)g,
      (__attribute__((address_space(3))) void*)l, 16, 0, 0);
}

// ---------------- prep: wconv (row-major) + layout ----------------
__global__ __launch_bounds__(1024)
void prep_kernel(const float* __restrict__ W, unsigned short* __restrict__ Wb, int w4,
                 const float* __restrict__ iw, int P,
                 int* __restrict__ tokBase, int* __restrict__ tokMask, int NB_W) {
  int bid = blockIdx.x;
  int tid = threadIdx.x;
  if (bid < NB_W) {
    int idx = bid * 1024 + tid;
    if (idx < w4) {
      float4 f = *(const float4*)(W + (size_t)idx * 4);
      ushort4 o;
      o.x = f2bf(f.x); o.y = f2bf(f.y); o.z = f2bf(f.z); o.w = f2bf(f.w);
      *(ushort4*)(Wb + (size_t)idx * 4) = o;
    }
    return;
  }
  // ---- layout (single block, r2-verified) ----
  __shared__ double s_wsum[16];
  __shared__ double s_avg;
  __shared__ int s_cnt[1024];
  float v = (tid < P) ? iw[tid] : 0.0f;
  double d = (double)v;
#pragma unroll
  for (int off = 32; off > 0; off >>= 1) d += __shfl_down(d, off, 64);
  if ((tid & 63) == 0) s_wsum[tid >> 6] = d;
  __syncthreads();
  if (tid == 0) {
    double s = 0.0;
    for (int i = 0; i < 16; ++i) s += s_wsum[i];
    s_avg = s / (double)P;
  }
  __syncthreads();
  int cnt = 0, sz = 32;
  if (tid < P) {
    double val = 32.0 * pow(s_avg / (double)v, 0.05);
    if (val > 32.0) val = 32.0;
    sz = (val >= 24.0) ? 32 : (val >= 12.0) ? 16 : (val >= 6.0) ? 8 : 4;
    cnt = (sz < 32) ? (32 / sz) : 1;
  }
  s_cnt[tid] = cnt;
  __syncthreads();
  for (int dl = 1; dl < 1024; dl <<= 1) {
    int add = (tid >= dl) ? s_cnt[tid - dl] : 0;
    __syncthreads();
    s_cnt[tid] += add;
    __syncthreads();
  }
  if (tid < P) {
    int off = s_cnt[tid] - cnt;
    int ini_col = (tid * 32) & 1023;
    int ini_row = (tid * 32 * 32) >> 10;
    if (sz == 32) {
      tokBase[off] = ini_row * 1024 + ini_col;
      tokMask[off] = 31;
    } else {
      int ns = 32 / sz;
      for (int j = 0; j < ns; ++j) {
        int r = ini_row + (j * sz) / ns;
        int c = ini_col + ((j * sz) & 31);
        tokBase[off + j] = r * 1024 + c;
        tokMask[off + j] = sz - 1;
      }
    }
  }
}

// ---------------- gather: row-major Ab, one block per A row (r3/r4-verified) ---
__global__ __launch_bounds__(256)
void gather_kernel(const float* __restrict__ x,
                   const int* __restrict__ tokBase,
                   const int* __restrict__ tokMask,
                   unsigned short* __restrict__ Ab) {
  int t = blockIdx.x;
  int b = blockIdx.y;
  int T = gridDim.x;
  int m = b * T + t;
  int base = tokBase[t];
  int mask = tokMask[t];
  int sh = __popc(mask);
  const float* xb = x + (size_t)b * 3145728 + (size_t)base;
  unsigned short* arow = Ab + (size_t)m * K_DIM;
#pragma unroll
  for (int it = 0; it < 3; ++it) {
    int g = it * 256 + threadIdx.x;
    int p = g * 4;
    int c = p >> 10;
    int f = p & 1023;
    int h = (f >> sh) & mask;
    int w = f & mask;
    float4 fv = *(const float4*)(xb + (size_t)c * 1048576 + h * 1024 + w);
    ushort4 o;
    o.x = f2bf(fv.x); o.y = f2bf(fv.y); o.z = f2bf(fv.z); o.w = f2bf(fv.w);
    *(ushort4*)(arow + p) = o;
  }
}

// ---------------- gemm: 128x128 x BK64, dbuf LDS, 1 barrier/iter --------------
__global__ __launch_bounds__(256, 2)
void gemm_kernel(const unsigned short* __restrict__ A, const unsigned short* __restrict__ Wb,
                 const float* __restrict__ bias, float* __restrict__ out, int Mtot) {
  // two buffers, each: A 128x64 (16 KB) + B 128x64 (16 KB); row = 128 B,
  // 16B-chunk c of row r stored at slot c^(r&7) (swizzle applied in src addr).
  __shared__ unsigned short lds[2][2][128 * 64];   // [buf][A/B][...]
  int tid = threadIdx.x;
  int lane = tid & 63;
  int wave = tid >> 6;
  int wr = wave >> 1, wc = wave & 1;
  int mBase = blockIdx.y * 128;
  int nBase = blockIdx.x * 128;

  f32x4 acc[4][4] = {};

  // staging: wave stages rows [wave*32, wave*32+32), 4 gll insts of 1 KB each
  // per operand. Per inst: row = wave*32 + inst*8 + (lane>>3); chunk slot =
  // lane&7 at LDS; source chunk = (lane&7)^(lane>>3)  (row&7 == lane>>3).
  int lrow = lane >> 3;
  int schunk = (lane & 7) ^ lrow;                  // swizzled source chunk
  const unsigned short* Ag = A + (size_t)(mBase + wave * 32 + lrow) * K_DIM + schunk * 8;
  const unsigned short* Bg = Wb + (size_t)(nBase + wave * 32 + lrow) * K_DIM + schunk * 8;
  unsigned short* Adst0 = &lds[0][0][(wave * 32) * 64] + lane * 8;  // +inst*8*64
  unsigned short* Bdst0 = &lds[0][1][(wave * 32) * 64] + lane * 8;

#define STAGE(BUF, KOFF)                                                    \
  {                                                                         \
    _Pragma("unroll")                                                       \
    for (int inst = 0; inst < 4; ++inst) {                                  \
      gload16(Ag + (size_t)(inst * 8) * K_DIM + (KOFF),                     \
              Adst0 + (size_t)(BUF) * 2 * 8192 + inst * 512);               \
      gload16(Bg + (size_t)(inst * 8) * K_DIM + (KOFF),                     \
              Bdst0 + (size_t)(BUF) * 2 * 8192 + inst * 512);               \
    }                                                                       \
  }

  int rr = lane & 15, q = lane >> 4;
  int r7 = rr & 7;

#define COMPUTE(BUF)                                                        \
  {                                                                         \
    const unsigned short* Ab_ = &lds[BUF][0][0];                            \
    const unsigned short* Bb_ = &lds[BUF][1][0];                            \
    _Pragma("unroll")                                                       \
    for (int kh = 0; kh < 2; ++kh) {                                        \
      bf16x8 aF[4], bF[4];                                                  \
      _Pragma("unroll")                                                     \
      for (int i = 0; i < 4; ++i)                                           \
        aF[i] = *(const bf16x8*)&Ab_[(wr * 64 + i * 16 + rr) * 64 +         \
                                     ((kh * 4 + q) ^ r7) * 8];              \
      _Pragma("unroll")                                                     \
      for (int j = 0; j < 4; ++j)                                           \
        bF[j] = *(const bf16x8*)&Bb_[(wc * 64 + j * 16 + rr) * 64 +         \
                                     ((kh * 4 + q) ^ r7) * 8];              \
      _Pragma("unroll")                                                     \
      for (int i = 0; i < 4; ++i)                                           \
        _Pragma("unroll")                                                   \
        for (int j = 0; j < 4; ++j)                                         \
          acc[i][j] = __builtin_amdgcn_mfma_f32_16x16x32_bf16(aF[i], bF[j], \
                                                              acc[i][j], 0, 0, 0); \
    }                                                                       \
  }

  STAGE(0, 0)
  __syncthreads();                 // buf0 ready
  int buf = 0;
  for (int k0 = 0; k0 < K_DIM; k0 += 64) {
    if (k0 + 64 < K_DIM) {
      if (buf == 0) STAGE(1, k0 + 64) else STAGE(0, k0 + 64)
    }
    if (buf == 0) COMPUTE(0) else COMPUTE(1)
    __syncthreads();               // drains next-tile gll; ds_reads retired
    buf ^= 1;
  }
#undef STAGE
#undef COMPUTE

  // epilogue: C/D layout col=lane&15, row=(lane>>4)*4+reg (r2-verified)
#pragma unroll
  for (int j = 0; j < 4; ++j) {
    int n = nBase + wc * 64 + j * 16 + rr;
    float bv = bias[n];
#pragma unroll
    for (int i = 0; i < 4; ++i) {
      int mrow = mBase + wr * 64 + i * 16 + q * 4;
#pragma unroll
      for (int r2 = 0; r2 < 4; ++r2) {
        int m = mrow + r2;
        if (m < Mtot) out[(size_t)m * N_DIM + n] = acc[i][j][r2] + bv;
      }
    }
  }
}

extern "C" void kernel_launch(void* const* d_in, const int* in_sizes, int n_in,
                              void* d_out, int out_size, void* d_ws, size_t ws_size,
                              hipStream_t stream) {
  const float* x  = (const float*)d_in[0];
  const float* iw = (const float*)d_in[1];
  const float* W  = (const float*)d_in[2];
  const float* b  = (const float*)d_in[3];
  int P = in_sizes[1];                        // 992
  int B = in_sizes[0] / (3 * 1024 * 1024);    // 8
  int E = in_sizes[3];                        // 768
  int T = out_size / (B * E);                 // 995
  int Mtot = B * T;                           // 7960
  int Mpad = (Mtot + 127) & ~127;             // 8064

  char* ws = (char*)d_ws;
  int* tokBase = (int*)ws;                              // 32 KB
  int* tokMask = (int*)(ws + 32768);                    // 32 KB
  unsigned short* Wb = (unsigned short*)(ws + 65536);   // 4.72 MB row-major
  unsigned short* Ab = (unsigned short*)(ws + 65536 + (size_t)E * K_DIM * 2);

  int w4 = E * K_DIM / 4;                     // 589824
  int NB_W = (w4 + 1023) / 1024;              // 576
  prep_kernel<<<NB_W + 1, 1024, 0, stream>>>(W, Wb, w4, iw, P, tokBase, tokMask, NB_W);

  dim3 gGrid(T, B);
  gather_kernel<<<gGrid, 256, 0, stream>>>(x, tokBase, tokMask, Ab);

  // zero-fill pad rows of Ab so gemm never stages poison into MFMA (harmless
  // but keep it clean): pad region is small (104 rows) — reuse gather? skip;
  // epilogue guards m<Mtot and bf16 poison is finite, so no fill needed.

  dim3 grid(N_DIM / 128, Mpad / 128);         // (6, 63) = 378 blocks
  gemm_kernel<<<grid, 256, 0, stream>>>(Ab, Wb, b, (float*)d_out, Mtot);
}